// Round 1
// baseline (26.490 us; speedup 1.0000x reference)
//
#include <hip/hip_runtime.h>

#define B_    4
#define N_    256
#define C_    256
#define OUTN  7
#define C4    (C_ / 4)   // 64 float4 groups per pixel

__global__ __launch_bounds__(256) void roi_pool_kernel(
    const float* __restrict__ f0, const float* __restrict__ f1,
    const float* __restrict__ f2, const float* __restrict__ f3,
    const float* __restrict__ f4, const float* __restrict__ boxes,
    float* __restrict__ out)
{
    const int bid = blockIdx.x;          // b*N + n
    const int b   = bid >> 8;            // N_ == 256
    const int tid = threadIdx.x;

    // ---- per-box scalar params (computed redundantly by all threads) ----
    const float* bx = boxes + (size_t)bid * 4;
    const float y1 = bx[0], x1 = bx[1], y2 = bx[2], x2 = bx[3];
    const float bh = y2 - y1, bw = x2 - x1;
    const float area_sqrt = sqrtf(bh * bw);
    const float lvf = floorf(logf(area_sqrt / 224.0f) / logf(2.0f)) + 4.0f;
    int levels = (int)lvf;
    levels = min(max(levels, 4), 64);
    const int   lvl    = levels - 4;
    const float scale  = exp2f((float)levels);
    const float stride = exp2f((float)lvl);
    const float bnd    = 128.0f / stride - 1.0f;   // bnd_h == bnd_w in ref
    const float box_y  = y1 / scale - 0.5f;
    const float box_x  = x1 / scale - 0.5f;
    const float bh_s   = bh / scale;
    const float bw_s   = bw / scale;

    // ---- per-bin sample coords & bilinear weights, staged in LDS ----
    __shared__ int   syi0[OUTN], syi1[OUTN], sxi0[OUTN], sxi1[OUTN];
    __shared__ float sly[OUTN], slx[OUTN];

    if (tid < 2 * OUTN) {
        const int   axis = tid / OUTN;             // 0 = y, 1 = x
        const int   s    = tid % OUTN;
        const float off  = ((float)s + 0.5f) / 7.0f;
        const float g    = (axis == 0) ? (box_y + off * bh_s)
                                       : (box_x + off * bw_s);
        const float p0 = fmaxf(0.0f, floorf(g));
        const float l  = g - p0;                   // can be <0 or >1 at edges (ref semantics)
        const int   i0 = (int)fminf(p0, bnd);
        const int   i1 = (int)fminf(p0 + 1.0f, bnd);
        if (axis == 0) { syi0[s] = i0; syi1[s] = i1; sly[s] = l; }
        else           { sxi0[s] = i0; sxi1[s] = i1; slx[s] = l; }
    }
    __syncthreads();

    // ---- select feature level (jnp gather clamps level index to [0,4]) ----
    const int lg = lvl > 4 ? 4 : lvl;
    const float* feat; int fs;
    switch (lg) {
        case 0:  feat = f0; fs = 128; break;
        case 1:  feat = f1; fs = 64;  break;
        case 2:  feat = f2; fs = 32;  break;
        case 3:  feat = f3; fs = 16;  break;
        default: feat = f4; fs = 8;   break;
    }
    const float4* fb = (const float4*)(feat) + (size_t)b * fs * fs * C4;
    float4*       ob = (float4*)(out) + (size_t)bid * (OUTN * OUTN * C4);
    const int rowstride = fs * C4;                 // float4 units per image row

    // ---- main loop: thread per (bin, c4); 64 lanes share a bin -> coalesced ----
    for (int i = tid; i < OUTN * OUTN * C4; i += 256) {
        const int c4  = i & (C4 - 1);
        const int bin = i >> 6;
        const int oy  = bin / 7;
        const int ox  = bin - oy * 7;

        const float ly = sly[oy], lx = slx[ox];
        const float hy = 1.0f - ly, hx = 1.0f - lx;
        const int y0 = syi0[oy], y1i = syi1[oy];
        const int x0 = sxi0[ox], x1i = sxi1[ox];

        const float4* r0 = fb + y0  * rowstride;
        const float4* r1 = fb + y1i * rowstride;
        const float4 f00 = r0[x0  * C4 + c4];
        const float4 f01 = r0[x1i * C4 + c4];
        const float4 f10 = r1[x0  * C4 + c4];
        const float4 f11 = r1[x1i * C4 + c4];

        const float w00 = hy * hx, w01 = hy * lx;
        const float w10 = ly * hx, w11 = ly * lx;

        float4 o;
        o.x = w00 * f00.x + w01 * f01.x + w10 * f10.x + w11 * f11.x;
        o.y = w00 * f00.y + w01 * f01.y + w10 * f10.y + w11 * f11.y;
        o.z = w00 * f00.z + w01 * f01.z + w10 * f10.z + w11 * f11.z;
        o.w = w00 * f00.w + w01 * f01.w + w10 * f10.w + w11 * f11.w;
        ob[i] = o;
    }
}

extern "C" void kernel_launch(void* const* d_in, const int* in_sizes, int n_in,
                              void* d_out, int out_size, void* d_ws, size_t ws_size,
                              hipStream_t stream) {
    const float* f0    = (const float*)d_in[0];
    const float* f1    = (const float*)d_in[1];
    const float* f2    = (const float*)d_in[2];
    const float* f3    = (const float*)d_in[3];
    const float* f4    = (const float*)d_in[4];
    const float* boxes = (const float*)d_in[5];
    float*       outp  = (float*)d_out;

    roi_pool_kernel<<<B_ * N_, 256, 0, stream>>>(f0, f1, f2, f3, f4, boxes, outp);
}

// Round 2
// 16.213 us; speedup vs baseline: 1.6338x; 1.6338x over previous
//
#include <hip/hip_runtime.h>

#define B_    4
#define N_    256
#define C_    256
#define OUTN  7
#define C4    (C_ / 4)   // 64 float4 groups per pixel

typedef float f32x4 __attribute__((ext_vector_type(4)));

__global__ __launch_bounds__(256) void roi_pool_kernel(
    const float* __restrict__ f0, const float* __restrict__ f1,
    const float* __restrict__ f2, const float* __restrict__ f3,
    const float* __restrict__ f4, const float* __restrict__ boxes,
    float* __restrict__ out)
{
    // ---- XCD-aware block->box swizzle ----
    // Hardware round-robins blocks over 8 XCDs (block i -> XCD i%8).
    // Give each XCD boxes from ONE batch image so its ~3.3MB touched
    // feature region fits the 4MiB per-XCD L2. Bijective on [0,1024).
    const int i_   = blockIdx.x;
    const int xcd  = i_ & 7;
    const int j_   = i_ >> 3;                 // 0..127
    const int bid  = (xcd >> 1) * N_ + (xcd & 1) * 128 + j_;   // b*N + n
    const int b    = bid >> 8;                // N_ == 256
    const int tid  = threadIdx.x;

    // ---- per-box scalar params (computed redundantly by all threads) ----
    const float* bx = boxes + (size_t)bid * 4;
    const float y1 = bx[0], x1 = bx[1], y2 = bx[2], x2 = bx[3];
    const float bh = y2 - y1, bw = x2 - x1;
    const float area_sqrt = sqrtf(bh * bw);
    const float lvf = floorf(logf(area_sqrt / 224.0f) / logf(2.0f)) + 4.0f;
    int levels = (int)lvf;
    levels = min(max(levels, 4), 64);
    const int   lvl    = levels - 4;
    const float scale  = exp2f((float)levels);
    const float stride = exp2f((float)lvl);
    const float bnd    = 128.0f / stride - 1.0f;   // bnd_h == bnd_w in ref
    const float box_y  = y1 / scale - 0.5f;
    const float box_x  = x1 / scale - 0.5f;
    const float bh_s   = bh / scale;
    const float bw_s   = bw / scale;

    // ---- per-bin sample coords & bilinear weights, staged in LDS ----
    __shared__ int   syi0[OUTN], syi1[OUTN], sxi0[OUTN], sxi1[OUTN];
    __shared__ float sly[OUTN], slx[OUTN];

    if (tid < 2 * OUTN) {
        const int   axis = tid / OUTN;             // 0 = y, 1 = x
        const int   s    = tid % OUTN;
        const float off  = ((float)s + 0.5f) / 7.0f;
        const float g    = (axis == 0) ? (box_y + off * bh_s)
                                       : (box_x + off * bw_s);
        const float p0 = fmaxf(0.0f, floorf(g));
        const float l  = g - p0;                   // can be <0 or >1 at edges (ref semantics)
        const int   i0 = (int)fminf(p0, bnd);
        const int   i1 = (int)fminf(p0 + 1.0f, bnd);
        if (axis == 0) { syi0[s] = i0; syi1[s] = i1; sly[s] = l; }
        else           { sxi0[s] = i0; sxi1[s] = i1; slx[s] = l; }
    }
    __syncthreads();

    // ---- select feature level (jnp gather clamps level index to [0,4]) ----
    const int lg = lvl > 4 ? 4 : lvl;
    const float* feat; int fs;
    switch (lg) {
        case 0:  feat = f0; fs = 128; break;
        case 1:  feat = f1; fs = 64;  break;
        case 2:  feat = f2; fs = 32;  break;
        case 3:  feat = f3; fs = 16;  break;
        default: feat = f4; fs = 8;   break;
    }
    const f32x4* fb = (const f32x4*)(feat) + (size_t)b * fs * fs * C4;
    f32x4*       ob = (f32x4*)(out) + (size_t)bid * (OUTN * OUTN * C4);
    const int rowstride = fs * C4;                 // float4 units per image row

    // ---- main loop: thread per (bin, c4); 64 lanes share a bin -> coalesced ----
    for (int i = tid; i < OUTN * OUTN * C4; i += 256) {
        const int c4  = i & (C4 - 1);
        const int bin = i >> 6;
        const int oy  = bin / 7;
        const int ox  = bin - oy * 7;

        const float ly = sly[oy], lx = slx[ox];
        const float hy = 1.0f - ly, hx = 1.0f - lx;
        const int y0 = syi0[oy], y1i = syi1[oy];
        const int x0 = sxi0[ox], x1i = sxi1[ox];

        const f32x4* r0 = fb + y0  * rowstride;
        const f32x4* r1 = fb + y1i * rowstride;
        const f32x4 f00 = r0[x0  * C4 + c4];
        const f32x4 f01 = r0[x1i * C4 + c4];
        const f32x4 f10 = r1[x0  * C4 + c4];
        const f32x4 f11 = r1[x1i * C4 + c4];

        const float w00 = hy * hx, w01 = hy * lx;
        const float w10 = ly * hx, w11 = ly * lx;

        f32x4 o = w00 * f00 + w01 * f01 + w10 * f10 + w11 * f11;
        // Nontemporal: the 51MB output stream is never re-read by us;
        // keep it from evicting the L2-resident feature tiles.
        __builtin_nontemporal_store(o, &ob[i]);
    }
}

extern "C" void kernel_launch(void* const* d_in, const int* in_sizes, int n_in,
                              void* d_out, int out_size, void* d_ws, size_t ws_size,
                              hipStream_t stream) {
    const float* f0    = (const float*)d_in[0];
    const float* f1    = (const float*)d_in[1];
    const float* f2    = (const float*)d_in[2];
    const float* f3    = (const float*)d_in[3];
    const float* f4    = (const float*)d_in[4];
    const float* boxes = (const float*)d_in[5];
    float*       outp  = (float*)d_out;

    roi_pool_kernel<<<B_ * N_, 256, 0, stream>>>(f0, f1, f2, f3, f4, boxes, outp);
}

// Round 3
// 15.679 us; speedup vs baseline: 1.6895x; 1.0340x over previous
//
#include <hip/hip_runtime.h>

#define B_    4
#define N_    256
#define C_    256
#define OUTN  7
#define C4    (C_ / 4)   // 64 float4 groups per pixel

typedef float f32x4 __attribute__((ext_vector_type(4)));

// 512 threads/block, 1 block per box: 1024 blocks x 512 = 2048 thr/CU
// = 32 waves/CU (100% occupancy) vs 16 waves at 256/block.
__global__ __launch_bounds__(512) void roi_pool_kernel(
    const float* __restrict__ f0, const float* __restrict__ f1,
    const float* __restrict__ f2, const float* __restrict__ f3,
    const float* __restrict__ f4, const float* __restrict__ boxes,
    float* __restrict__ out)
{
    // ---- XCD-aware block->box swizzle ----
    // Block i -> XCD i%8. Give each XCD boxes from ONE batch image so its
    // ~3.3MB touched feature region fits the 4MiB per-XCD L2.
    const int i_   = blockIdx.x;
    const int xcd  = i_ & 7;
    const int j_   = i_ >> 3;                 // 0..127
    const int bid  = (xcd >> 1) * N_ + (xcd & 1) * 128 + j_;   // b*N + n
    const int b    = bid >> 8;                // N_ == 256
    const int tid  = threadIdx.x;

    // ---- per-box scalar params (computed redundantly by all threads) ----
    const float* bx = boxes + (size_t)bid * 4;
    const float y1 = bx[0], x1 = bx[1], y2 = bx[2], x2 = bx[3];
    const float bh = y2 - y1, bw = x2 - x1;
    const float area_sqrt = sqrtf(bh * bw);
    const float lvf = floorf(logf(area_sqrt / 224.0f) / logf(2.0f)) + 4.0f;
    int levels = (int)lvf;
    levels = min(max(levels, 4), 64);
    const int   lvl    = levels - 4;
    const float scale  = exp2f((float)levels);
    const float stride = exp2f((float)lvl);
    const float bnd    = 128.0f / stride - 1.0f;   // bnd_h == bnd_w in ref
    const float box_y  = y1 / scale - 0.5f;
    const float box_x  = x1 / scale - 0.5f;
    const float bh_s   = bh / scale;
    const float bw_s   = bw / scale;

    // ---- per-bin sample coords & bilinear weights, staged in LDS ----
    __shared__ int   syi0[OUTN], syi1[OUTN], sxi0[OUTN], sxi1[OUTN];
    __shared__ float sly[OUTN], slx[OUTN];

    if (tid < 2 * OUTN) {
        const int   axis = tid / OUTN;             // 0 = y, 1 = x
        const int   s    = tid % OUTN;
        const float off  = ((float)s + 0.5f) / 7.0f;
        const float g    = (axis == 0) ? (box_y + off * bh_s)
                                       : (box_x + off * bw_s);
        const float p0 = fmaxf(0.0f, floorf(g));
        const float l  = g - p0;                   // can be <0 or >1 at edges (ref semantics)
        const int   i0 = (int)fminf(p0, bnd);
        const int   i1 = (int)fminf(p0 + 1.0f, bnd);
        if (axis == 0) { syi0[s] = i0; syi1[s] = i1; sly[s] = l; }
        else           { sxi0[s] = i0; sxi1[s] = i1; slx[s] = l; }
    }
    __syncthreads();

    // ---- select feature level (jnp gather clamps level index to [0,4]) ----
    const int lg = lvl > 4 ? 4 : lvl;
    const float* feat; int fs;
    switch (lg) {
        case 0:  feat = f0; fs = 128; break;
        case 1:  feat = f1; fs = 64;  break;
        case 2:  feat = f2; fs = 32;  break;
        case 3:  feat = f3; fs = 16;  break;
        default: feat = f4; fs = 8;   break;
    }
    const f32x4* fb = (const f32x4*)(feat) + (size_t)b * fs * fs * C4;
    f32x4*       ob = (f32x4*)(out) + (size_t)bid * (OUTN * OUTN * C4);
    const int rowstride = fs * C4;                 // float4 units per image row

    // ---- main loop: thread per (bin, c4); 64 lanes share a bin -> coalesced ----
    #pragma unroll 2
    for (int i = tid; i < OUTN * OUTN * C4; i += 512) {
        const int c4  = i & (C4 - 1);
        const int bin = i >> 6;
        const int oy  = bin / 7;
        const int ox  = bin - oy * 7;

        const float ly = sly[oy], lx = slx[ox];
        const float hy = 1.0f - ly, hx = 1.0f - lx;
        const int y0 = syi0[oy], y1i = syi1[oy];
        const int x0 = sxi0[ox], x1i = sxi1[ox];

        const f32x4* r0 = fb + y0  * rowstride;
        const f32x4* r1 = fb + y1i * rowstride;
        const f32x4 f00 = r0[x0  * C4 + c4];
        const f32x4 f01 = r0[x1i * C4 + c4];
        const f32x4 f10 = r1[x0  * C4 + c4];
        const f32x4 f11 = r1[x1i * C4 + c4];

        const float w00 = hy * hx, w01 = hy * lx;
        const float w10 = ly * hx, w11 = ly * lx;

        f32x4 o = w00 * f00 + w01 * f01 + w10 * f10 + w11 * f11;
        // Nontemporal: the 51MB output stream is never re-read by us;
        // keep it from evicting the L2-resident feature tiles.
        __builtin_nontemporal_store(o, &ob[i]);
    }
}

extern "C" void kernel_launch(void* const* d_in, const int* in_sizes, int n_in,
                              void* d_out, int out_size, void* d_ws, size_t ws_size,
                              hipStream_t stream) {
    const float* f0    = (const float*)d_in[0];
    const float* f1    = (const float*)d_in[1];
    const float* f2    = (const float*)d_in[2];
    const float* f3    = (const float*)d_in[3];
    const float* f4    = (const float*)d_in[4];
    const float* boxes = (const float*)d_in[5];
    float*       outp  = (float*)d_out;

    roi_pool_kernel<<<B_ * N_, 512, 0, stream>>>(f0, f1, f2, f3, f4, boxes, outp);
}

// Round 4
// 15.453 us; speedup vs baseline: 1.7143x; 1.0147x over previous
//
#include <hip/hip_runtime.h>

#define B_    4
#define N_    256
#define C_    256
#define OUTN  7
#define NBIN  49          // 7x7 bins
#define C4    64          // float4 groups per pixel (1 KiB per pixel)

typedef float f32x4 __attribute__((ext_vector_type(4)));

struct __align__(16) BinInfo {
    float    w00, w01, w10, w11;   // bilinear weights
    unsigned yb0, yb1, xb0, xb1;   // byte offsets: row0/row1, col0/col1
};

// 512 thr/block (8 waves), 1 block/box, 4 blocks/CU = 32 waves/CU.
// lane = c4 channel group; wave handles bins wv, wv+8, ... -> every value
// except the blend operands is wave-uniform.
__global__ __launch_bounds__(512) void roi_pool_kernel(
    const float* __restrict__ f0, const float* __restrict__ f1,
    const float* __restrict__ f2, const float* __restrict__ f3,
    const float* __restrict__ f4, const float* __restrict__ boxes,
    float* __restrict__ out)
{
    // ---- XCD-aware block->box swizzle (R2 win: L2 locality) ----
    const int i_   = blockIdx.x;
    const int xcd  = i_ & 7;
    const int j_   = i_ >> 3;
    const int bid  = (xcd >> 1) * N_ + (xcd & 1) * 128 + j_;   // b*N + n
    const int b    = bid >> 8;
    const int tid  = threadIdx.x;
    const int lane = tid & 63;
    const int wv   = tid >> 6;

    // ---- per-box scalar params ----
    const float* bx = boxes + (size_t)bid * 4;
    const float y1 = bx[0], x1 = bx[1], y2 = bx[2], x2 = bx[3];
    const float bh = y2 - y1, bw = x2 - x1;
    const float area_sqrt = sqrtf(bh * bw);
    const float lvf = floorf(logf(area_sqrt / 224.0f) / logf(2.0f)) + 4.0f;
    int levels = (int)lvf;
    levels = min(max(levels, 4), 64);
    const int   lvl    = levels - 4;
    const float scale  = exp2f((float)levels);
    const float stride = exp2f((float)lvl);
    const float bnd    = 128.0f / stride - 1.0f;
    const float box_y  = y1 / scale - 0.5f;
    const float box_x  = x1 / scale - 0.5f;
    const float bh_s   = bh / scale;
    const float bw_s   = bw / scale;

    // ---- feature level (jnp gather clamps level index to [0,4]) ----
    const int lg = lvl > 4 ? 4 : lvl;
    const float* feat; int fs;
    switch (lg) {
        case 0:  feat = f0; fs = 128; break;
        case 1:  feat = f1; fs = 64;  break;
        case 2:  feat = f2; fs = 32;  break;
        case 3:  feat = f3; fs = 16;  break;
        default: feat = f4; fs = 8;   break;
    }

    // ---- per-bin params: 4 weights + 4 byte offsets, staged in LDS ----
    __shared__ BinInfo sbin[NBIN];
    if (tid < NBIN) {
        const int oy = tid / 7;
        const int ox = tid - oy * 7;
        const float gy = box_y + (((float)oy + 0.5f) * (1.0f / 7.0f)) * bh_s;
        const float gx = box_x + (((float)ox + 0.5f) * (1.0f / 7.0f)) * bw_s;
        const float py = fmaxf(0.0f, floorf(gy));
        const float px = fmaxf(0.0f, floorf(gx));
        const float ly = gy - py, lx = gx - px;   // may be <0/>1 at edges (ref semantics)
        const float hy = 1.0f - ly, hx = 1.0f - lx;
        const int y0  = (int)fminf(py,        bnd);
        const int y1i = (int)fminf(py + 1.0f, bnd);
        const int x0  = (int)fminf(px,        bnd);
        const int x1i = (int)fminf(px + 1.0f, bnd);
        BinInfo bi;
        bi.w00 = hy * hx; bi.w01 = hy * lx;
        bi.w10 = ly * hx; bi.w11 = ly * lx;
        bi.yb0 = (unsigned)(y0  * fs) << 10;      // row byte offset (fs px * 1KiB)
        bi.yb1 = (unsigned)(y1i * fs) << 10;
        bi.xb0 = (unsigned)x0 << 10;              // col byte offset
        bi.xb1 = (unsigned)x1i << 10;
        sbin[tid] = bi;
    }
    __syncthreads();

    // uniform 64-bit bases; all per-corner addressing is 32-bit offsets
    const char* fbB  = (const char*)feat + (size_t)b * fs * fs * 1024;
    char*       obB  = (char*)out + (size_t)bid * (NBIN * 1024);
    const unsigned laneB = (unsigned)lane << 4;

    #pragma unroll 2
    for (int bin = wv; bin < NBIN; bin += 8) {
        const BinInfo bi = sbin[bin];             // 2x ds_read_b128, uniform addr
        const f32x4 f00 = *(const f32x4*)(fbB + (bi.yb0 + bi.xb0 + laneB));
        const f32x4 f01 = *(const f32x4*)(fbB + (bi.yb0 + bi.xb1 + laneB));
        const f32x4 f10 = *(const f32x4*)(fbB + (bi.yb1 + bi.xb0 + laneB));
        const f32x4 f11 = *(const f32x4*)(fbB + (bi.yb1 + bi.xb1 + laneB));
        f32x4 o = bi.w00 * f00 + bi.w01 * f01 + bi.w10 * f10 + bi.w11 * f11;
        // NT store: keep the 51MB write stream from evicting L2-resident features
        __builtin_nontemporal_store(o, (f32x4*)(obB + (((unsigned)bin << 10) + laneB)));
    }
}

extern "C" void kernel_launch(void* const* d_in, const int* in_sizes, int n_in,
                              void* d_out, int out_size, void* d_ws, size_t ws_size,
                              hipStream_t stream) {
    const float* f0    = (const float*)d_in[0];
    const float* f1    = (const float*)d_in[1];
    const float* f2    = (const float*)d_in[2];
    const float* f3    = (const float*)d_in[3];
    const float* f4    = (const float*)d_in[4];
    const float* boxes = (const float*)d_in[5];
    float*       outp  = (float*)d_out;

    roi_pool_kernel<<<B_ * N_, 512, 0, stream>>>(f0, f1, f2, f3, f4, boxes, outp);
}